// Round 1
// baseline (107.379 us; speedup 1.0000x reference)
//
#include <hip/hip_runtime.h>

#define BATCH 2
#define KK    2
#define NN    512
#define DOBS  32
#define DIN   64
#define DOUT  32

// ---------------------------------------------------------------------------
// K1: Xc[b,k,i,:] = X[b,k,i,:] @ W_in + b_in     rows = B*3*N = 3072
// block 256 = 4 rows x 64 d-lanes
// ---------------------------------------------------------------------------
__global__ void xc_kernel(const float* __restrict__ X, const float* __restrict__ W_in,
                          const float* __restrict__ b_in, float* __restrict__ Xc) {
    int t   = threadIdx.x;
    int row = blockIdx.x * 4 + (t >> 6);   // 0..3071
    int d   = t & 63;
    const float* x = X + row * DOBS;
    float acc = b_in[d];
#pragma unroll
    for (int o = 0; o < DOBS; ++o) acc += x[o] * W_in[o * DIN + d];
    Xc[row * DIN + d] = acc;
}

// ---------------------------------------------------------------------------
// K2: y2[b,i,:] = sum_j A[b,1,i,j] * Xc[b,2,j,:]   (one block per (b,i) row)
// ---------------------------------------------------------------------------
__global__ void y2_kernel(const float* __restrict__ A, const float* __restrict__ Xc,
                          float* __restrict__ y2) {
    __shared__ float arow[NN];
    __shared__ float red[256];
    int t   = threadIdx.x;
    int row = blockIdx.x;                 // b*N + i
    int b = row >> 9, i = row & 511;
    const float* a1 = A + (((size_t)b * KK + 1) * NN + i) * NN;   // A[b,1,i,:]
    for (int j = t; j < NN; j += 256) arow[j] = a1[j];
    __syncthreads();
    int d = t & 63, jg = t >> 6;
    const float* xc2 = Xc + ((size_t)(b * 3 + 2) * NN) * DIN;
    float acc = 0.f;
#pragma unroll 4
    for (int j = jg; j < NN; j += 4)
        acc += arow[j] * xc2[j * DIN + d];
    red[t] = acc;
    __syncthreads();
    if (t < 64)
        y2[row * DIN + t] = red[t] + red[64 + t] + red[128 + t] + red[192 + t];
}

// ---------------------------------------------------------------------------
// K3: P rows (no bias):  P layout [kk][b][j][d], kk in {0,1,2}
//   kk=0: Xc[b,0,j,:] @ W_pre     kk=1: Xc[b,1,j,:] @ W_pre
//   kk=2: y2[b,j,:]   @ W_pre
// rows = 3*B*N = 3072, block 256 = 4 rows x 64 lanes
// ---------------------------------------------------------------------------
__global__ void pq_kernel(const float* __restrict__ Xc, const float* __restrict__ y2,
                          const float* __restrict__ W_pre, float* __restrict__ P) {
    int t   = threadIdx.x;
    int row = blockIdx.x * 4 + (t >> 6);  // kk*(B*N) + b*N + j
    int d   = t & 63;
    int kk  = row / (BATCH * NN);
    int r   = row % (BATCH * NN);
    int b = r >> 9, j = r & 511;
    const float* src;
    if (kk == 0)      src = Xc + ((size_t)(b * 3 + 0) * NN + j) * DIN;
    else if (kk == 1) src = Xc + ((size_t)(b * 3 + 1) * NN + j) * DIN;
    else              src = y2 + ((size_t)b * NN + j) * DIN;
    float acc = 0.f;
#pragma unroll 16
    for (int o = 0; o < DIN; ++o) acc += src[o] * W_pre[o * DIN + d];
    P[row * DIN + d] = acc;
}

// ---------------------------------------------------------------------------
// K4: per (b,i) block:
//   inc1[d] = sum_j relu(A0[b,i,j]*P1[b,j,d] + b_pre[d])
//   inc2[d] = sum_j relu(A0[b,i,j]*Q2[b,j,d] + b_pre[d])
//   inc0[d] = relu(P0[b,i,d] + b_pre[d]) + (N-1)*relu(b_pre[d])
//   mid[k]  = relu(inc[k] @ W_mid + b_mid);  agg = sum_k mid[k]
//   out     = agg @ W_fin + b_fin
// ---------------------------------------------------------------------------
__global__ void main_kernel(const float* __restrict__ A, const float* __restrict__ P,
                            const float* __restrict__ b_pre,
                            const float* __restrict__ W_mid, const float* __restrict__ b_mid,
                            const float* __restrict__ W_fin, const float* __restrict__ b_fin,
                            float* __restrict__ out) {
    __shared__ float arow[NN];
    __shared__ float red[512];
    __shared__ float inc[3][DIN];
    __shared__ float mid[3][DIN];
    __shared__ float agg[DIN];
    int t   = threadIdx.x;
    int row = blockIdx.x;                 // b*N + i
    int b = row >> 9, i = row & 511;
    const float* a0 = A + (((size_t)b * KK + 0) * NN + i) * NN;   // A[b,0,i,:]
    for (int j = t; j < NN; j += 256) arow[j] = a0[j];
    __syncthreads();

    int d = t & 63, jg = t >> 6;
    const float* P1 = P + ((size_t)(1 * BATCH * NN) + b * NN) * DIN + d;
    const float* Q2 = P + ((size_t)(2 * BATCH * NN) + b * NN) * DIN + d;
    float bp = b_pre[d];
    float acc1 = 0.f, acc2 = 0.f;
#pragma unroll 4
    for (int j = jg; j < NN; j += 4) {
        float a = arow[j];
        acc1 += fmaxf(fmaf(a, P1[j * DIN], bp), 0.f);
        acc2 += fmaxf(fmaf(a, Q2[j * DIN], bp), 0.f);
    }
    red[t]       = acc1;
    red[256 + t] = acc2;
    __syncthreads();

    if (t < 64) {
        const float* P0 = P + ((size_t)(0 * BATCH * NN) + b * NN + i) * DIN;
        inc[0][t] = fmaxf(P0[t] + bp, 0.f) + (float)(NN - 1) * fmaxf(bp, 0.f);
        inc[1][t] = red[t]       + red[64 + t]  + red[128 + t] + red[192 + t];
        inc[2][t] = red[256 + t] + red[320 + t] + red[384 + t] + red[448 + t];
    }
    __syncthreads();

    if (t < 192) {
        int k = t >> 6;
        float acc = b_mid[d];
#pragma unroll 16
        for (int o = 0; o < DIN; ++o) acc += inc[k][o] * W_mid[o * DIN + d];
        mid[k][d] = fmaxf(acc, 0.f);
    }
    __syncthreads();

    if (t < 64) agg[t] = mid[0][t] + mid[1][t] + mid[2][t];
    __syncthreads();

    if (t < 32) {
        float acc = b_fin[t];
#pragma unroll 16
        for (int o = 0; o < DIN; ++o) acc += agg[o] * W_fin[o * DOUT + t];
        out[(size_t)row * DOUT + t] = acc;
    }
}

extern "C" void kernel_launch(void* const* d_in, const int* in_sizes, int n_in,
                              void* d_out, int out_size, void* d_ws, size_t ws_size,
                              hipStream_t stream) {
    const float* A     = (const float*)d_in[0];
    const float* X     = (const float*)d_in[1];
    const float* W_in  = (const float*)d_in[2];
    const float* b_in  = (const float*)d_in[3];
    const float* W_pre = (const float*)d_in[4];
    const float* b_pre = (const float*)d_in[5];
    const float* W_mid = (const float*)d_in[6];
    const float* b_mid = (const float*)d_in[7];
    const float* W_fin = (const float*)d_in[8];
    const float* b_fin = (const float*)d_in[9];
    float* out = (float*)d_out;

    float* ws = (float*)d_ws;
    float* Xc = ws;                     // B*3*N*DIN = 196608 floats
    float* y2 = ws + 196608;            // B*N*DIN   =  65536 floats
    float* P  = ws + 262144;            // 3*B*N*DIN = 196608 floats

    xc_kernel  <<<768,  256, 0, stream>>>(X, W_in, b_in, Xc);
    y2_kernel  <<<1024, 256, 0, stream>>>(A, Xc, y2);
    pq_kernel  <<<768,  256, 0, stream>>>(Xc, y2, W_pre, P);
    main_kernel<<<1024, 256, 0, stream>>>(A, P, b_pre, W_mid, b_mid, W_fin, b_fin, out);
}